// Round 1
// baseline (310.995 us; speedup 1.0000x reference)
//
#include <hip/hip_runtime.h>

// YOLO detection head post-process.
// Input : x (B=64, C=255, 52, 52) f32   [C = 3 anchors * 85]
// Output: (B, 3*52*52, 85) f32
// Per (b,a): transpose (85, 2704) -> (2704, 85) with pointwise transform:
//   e==0: (sigmoid(v) + cx) * 8
//   e==1: (sigmoid(v) + cy) * 8
//   e==2: exp(v) * AW[a]          (anchor/stride * stride cancels)
//   e==3: exp(v) * AH[a]
//   e>=4: sigmoid(v)

#define GRID 52
#define GG   2704      // 52*52
#define CH   85
#define TS   104       // spatial tile = 2 grid rows; 2704 / 104 = 26 exactly
#define NT   26
#define LSTR 105       // LDS row stride: 105 % 32 == 9, coprime with 32 -> conflict-free reads

__global__ __launch_bounds__(256) void det_kernel(const float* __restrict__ in,
                                                  float* __restrict__ out) {
    __shared__ float lds[CH * LSTR];   // 85*105*4 = 35,700 B -> 4 blocks/CU

    const int tile = blockIdx.x;   // 0..25
    const int a    = blockIdx.y;   // 0..2
    const int b    = blockIdx.z;   // 0..63
    const int tid  = threadIdx.x;

    // ---- Stage: global (coalesced float4 along s) -> LDS ----
    // base float offset: ((b*255 + a*85) * 2704) + tile*104  (multiple of 4 -> float4 aligned)
    const float4* in4 = (const float4*)(in + ((size_t)b * 255 + (size_t)a * 85) * GG
                                           + (size_t)tile * TS);
    // input row stride in float4 units: 2704/4 = 676
    #pragma unroll 4
    for (int l = tid; l < CH * (TS / 4); l += 256) {   // 85*26 = 2210 float4s
        int c  = l / 26;
        int s4 = l - c * 26;
        float4 v = in4[c * 676 + s4];
        float* dst = &lds[c * LSTR + s4 * 4];
        dst[0] = v.x; dst[1] = v.y; dst[2] = v.z; dst[3] = v.w;
    }
    __syncthreads();

    // ---- Transform + store: contiguous 8840-float output span per tile ----
    const float AW[3] = {10.f, 16.f, 33.f};
    const float AH[3] = {13.f, 30.f, 23.f};
    const float aw = AW[a], ah = AH[a];

    float* outp = out + ((size_t)b * (3 * GG) + (size_t)a * GG + (size_t)tile * TS) * CH;

    #pragma unroll 4
    for (int o = tid; o < TS * CH; o += 256) {   // 8840 floats
        int s = o / 85;          // local spatial within tile [0,104)
        int e = o - s * 85;      // output channel [0,85)
        float v = lds[e * LSTR + s];
        float r;
        if (e >= 4) {
            r = 1.f / (1.f + __expf(-v));              // class scores + nothing else
        } else if (e == 2) {
            r = __expf(v) * aw;
        } else if (e == 3) {
            r = __expf(v) * ah;
        } else if (e == 4) {
            r = 1.f / (1.f + __expf(-v));              // conf (covered by e>=4 path; kept for clarity)
        } else {
            // e==0 -> +cx, e==1 -> +cy ; tile*104 is a multiple of 52, so:
            float sig = 1.f / (1.f + __expf(-v));
            int  hi   = (s >= GRID) ? 1 : 0;
            float coord = (e == 0) ? (float)(s - hi * GRID)        // cx = s_g % 52
                                   : (float)(tile * 2 + hi);       // cy = s_g / 52
            r = (sig + coord) * 8.0f;
        }
        outp[o] = r;
    }
}

extern "C" void kernel_launch(void* const* d_in, const int* in_sizes, int n_in,
                              void* d_out, int out_size, void* d_ws, size_t ws_size,
                              hipStream_t stream) {
    const float* x = (const float*)d_in[0];
    float* out = (float*)d_out;
    dim3 grid(NT, 3, 64);   // 26 spatial tiles x 3 anchors x 64 batch = 4992 blocks
    det_kernel<<<grid, 256, 0, stream>>>(x, out);
}

// Round 2
// 304.085 us; speedup vs baseline: 1.0227x; 1.0227x over previous
//
#include <hip/hip_runtime.h>

// YOLO detection head post-process.
// Input : x (B=64, C=255, 52, 52) f32   [C = 3 anchors * 85]
// Output: (B, 3*52*52, 85) f32
// out[((b*3+a)*2704 + y*52 + x)*85 + e]:
//   e==0: (sigmoid(v) + x) * 8
//   e==1: (sigmoid(v) + y) * 8
//   e==2: exp(v) * AW[a]        (anchor/stride * stride cancels)
//   e==3: exp(v) * AH[a]
//   e>=4: sigmoid(v)

#define GG   2704      // 52*52
#define CH   85
#define TS   52        // spatial tile = 1 grid row -> cy is a block constant
#define LSTR 53        // 53 % 32 == 21, coprime with 32 -> conflict-free transposed reads

__global__ __launch_bounds__(256) void det_kernel(const float* __restrict__ in,
                                                  float* __restrict__ out) {
    __shared__ float lds[CH * LSTR];   // 85*53*4 = 18,020 B -> 8 blocks/CU

    const int tile = blockIdx.x;   // grid row y, 0..51
    const int a    = blockIdx.y;   // anchor 0..2
    const int b    = blockIdx.z;   // batch 0..63
    const int tid  = threadIdx.x;

    // ---- Stage: global (coalesced float4 along x) -> LDS ----
    const float4* in4 = (const float4*)(in + ((size_t)b * 255 + (size_t)a * 85) * GG
                                           + (size_t)tile * TS);
    // input row stride: 2704/4 = 676 float4s; 13 float4s per channel row
    for (int l = tid; l < CH * (TS / 4); l += 256) {   // 85*13 = 1105
        int c  = l / 13;
        int s4 = l - c * 13;
        float4 v = in4[c * 676 + s4];
        float* dst = &lds[c * LSTR + s4 * 4];
        dst[0] = v.x; dst[1] = v.y; dst[2] = v.z; dst[3] = v.w;
    }
    __syncthreads();

    // ---- Transform + store: e fixed per thread, all selection hoisted ----
    // Thread tid (<255) owns channel e = tid%85, starting x = tid/85, x += 3/pass.
    // Output offset o = x*85 + e = tid + 255*k : consecutive lanes -> coalesced.
    if (tid < 255) {
        const int e  = tid % 85;
        const int s0 = tid / 85;           // 0,1,2

        const float AW[3] = {10.f, 16.f, 33.f};
        const float AH[3] = {13.f, 30.f, 23.f};

        const bool  isexp = (e == 2) | (e == 3);
        const float sgn   = isexp ? 1.f : -1.f;
        float scale;
        if (e < 2)       scale = 8.f;
        else if (e == 2) scale = AW[a];
        else if (e == 3) scale = AH[a];
        else             scale = 1.f;
        float addend = (e == 0) ? 8.f * (float)s0
                     : (e == 1) ? 8.f * (float)tile : 0.f;
        const float adelta = (e == 0) ? 24.f : 0.f;   // x advances by 3 per pass

        float* op = out + ((size_t)((b * 3 + a) * GG) + (size_t)tile * TS) * CH;
        int idx = e * LSTR + s0;

        #pragma unroll 2
        for (int o = tid; o < TS * CH; o += 255, idx += 3) {   // 4420 outputs
            float v = lds[idx];
            float t = __expf(sgn * v);                         // v_mul + v_exp
            float w = isexp ? t : __builtin_amdgcn_rcpf(1.f + t);
            op[o] = fmaf(scale, w, addend);
            addend += adelta;
        }
    }
}

extern "C" void kernel_launch(void* const* d_in, const int* in_sizes, int n_in,
                              void* d_out, int out_size, void* d_ws, size_t ws_size,
                              hipStream_t stream) {
    const float* x = (const float*)d_in[0];
    float* out = (float*)d_out;
    dim3 grid(52, 3, 64);   // 52 rows x 3 anchors x 64 batch = 9984 blocks
    det_kernel<<<grid, 256, 0, stream>>>(x, out);
}